// Round 5
// baseline (800.503 us; speedup 1.0000x reference)
//
#include <hip/hip_runtime.h>
#include <cstdint>
#include <cstddef>

#define BATCH 8
#define SEQ   4096
#define DS    512
#define JPL   8              // states per lane (64 lanes * 8 = 512)
#define BLK   16             // time steps per LDS block
#define NBLK  (SEQ / BLK)    // 256 (even)

typedef float v2f __attribute__((ext_vector_type(2)));
typedef float v4f __attribute__((ext_vector_type(4)));

static __device__ __forceinline__ v2f lo2(v4f x) { return __builtin_shufflevector(x, x, 0, 1); }
static __device__ __forceinline__ v2f hi2(v4f x) { return __builtin_shufflevector(x, x, 2, 3); }

// ---- DPP wave64 reduction: row_shr 1/2/4/8, row_bcast15/31 -> lane 63 ----
template <int CTRL>
__device__ __forceinline__ float dpp_add(float v) {
  int t = __builtin_amdgcn_update_dpp(0, __builtin_bit_cast(int, v), CTRL, 0xF, 0xF, true);
  return v + __builtin_bit_cast(float, t);
}
__device__ __forceinline__ float wave_sum64(float v) {
  v = dpp_add<0x111>(v);
  v = dpp_add<0x112>(v);
  v = dpp_add<0x114>(v);
  v = dpp_add<0x118>(v);
  v = dpp_add<0x142>(v);
  v = dpp_add<0x143>(v);
  return v;  // valid in lane 63
}
// two independent chains interleaved: fills DPP wait states
__device__ __forceinline__ void wave_sum64x2(float& p, float& q) {
  p = dpp_add<0x111>(p); q = dpp_add<0x111>(q);
  p = dpp_add<0x112>(p); q = dpp_add<0x112>(q);
  p = dpp_add<0x114>(p); q = dpp_add<0x114>(q);
  p = dpp_add<0x118>(p); q = dpp_add<0x118>(q);
  p = dpp_add<0x142>(p); q = dpp_add<0x142>(q);
  p = dpp_add<0x143>(p); q = dpp_add<0x143>(q);
}
__device__ __forceinline__ float bcast63(float v) {
  return __builtin_bit_cast(float, __builtin_amdgcn_readlane(__builtin_bit_cast(int, v), 63));
}

// async HBM -> LDS: per-lane 16B from g, LDS dest = uniform base + lane*16
__device__ __forceinline__ void ld16(const float* g, float* l) {
  __builtin_amdgcn_global_load_lds(
      (const __attribute__((address_space(1))) void*)g,
      (__attribute__((address_space(3))) void*)l, 16, 0, 0);
}

// ---------------- scan kernel: 3 waves per batch element --------------------
// wave 0: consumer (recurrence; LDS-only, register-prefetched reads)
// wave 1: DMA x into LDS + reduce/store sealed blocks' readout scalars
// wave 2: rg = 1/(1+sigmoid(g)*v) into LDS (vol prefetched one interval ahead)
__global__ __launch_bounds__(192, 1) void ssm_scan(
    const float* __restrict__ x, const float* __restrict__ vol,
    const float* __restrict__ llr, const float* __restrict__ logb,
    const float* __restrict__ cvec, const float* __restrict__ lstp,
    const float* __restrict__ vgat, const float* __restrict__ lnw,
    const float* __restrict__ lnb, float* __restrict__ sp)
{
  __shared__ float X0[BLK * 512], X1[BLK * 512];   // x tiles
  __shared__ float R0[BLK * 512], R1[BLK * 512];   // rg tiles
  __shared__ float SC0[BLK * 64], SC1[BLK * 64];   // per-lane readout partials

  const int b    = blockIdx.x;
  const int lane = threadIdx.x & 63;
  const int wid  = threadIdx.x >> 6;

  if (wid == 1) {
    // ===================== DMA + reduce/copy wave =====================
    const float* xg = x + (size_t)b * SEQ * DS + lane * JPL;
    float* spb = sp + (size_t)b * SEQ;

    auto dma_blk = [&](int blk, float* Xs) {
#pragma unroll
      for (int u = 0; u < BLK; ++u) {
        const float* row = xg + (size_t)(blk * BLK + u) * DS;
        ld16(row,     Xs + u * 512);         // floats [8l..8l+3]
        ld16(row + 4, Xs + u * 512 + 256);   // floats [8l+4..8l+7]
      }
    };
    auto red_copy = [&](const float* SCs, int blk) {
      float s[BLK];
#pragma unroll
      for (int u = 0; u < BLK; ++u) s[u] = wave_sum64(SCs[u * 64 + lane]);
      if (lane == 63) {
#pragma unroll
        for (int u = 0; u < BLK; ++u) spb[blk * BLK + u] = s[u];
      }
    };

    dma_blk(0, X0);
    __syncthreads();  // B0: block 0 staged
#pragma unroll 1
    for (int i2 = 0; i2 < NBLK; i2 += 2) {
      dma_blk(i2 + 1, X1);                       // stage block i2+1
      if (i2 > 0) red_copy(SC1, i2 - 1);         // block i2-1 scalars (sealed)
      __syncthreads();
      if (i2 + 2 < NBLK) dma_blk(i2 + 2, X0);    // stage block i2+2
      red_copy(SC0, i2);                         // block i2 scalars (sealed)
      __syncthreads();
    }
    red_copy(SC1, NBLK - 1);                     // final block's scalars
  } else if (wid == 2) {
    // ===================== gate-reciprocal wave =====================
    v2f gate[4];
#pragma unroll
    for (int j = 0; j < JPL; ++j)
      gate[j >> 1][j & 1] = 1.0f / (1.0f + expf(-vgat[lane * JPL + j]));
    const float* vg = vol + (size_t)b * SEQ;

    auto rg_blk = [&](const v4f (&V)[4], float* Rs) {
#pragma unroll
      for (int u = 0; u < BLK; ++u) {
        float vt = V[u >> 2][u & 3];
        v4f r0, r1;
#pragma unroll
        for (int k = 0; k < 4; ++k) {
          v2f den = gate[k] * vt + 1.0f;
          float q0 = __builtin_amdgcn_rcpf(den.x);
          float q1 = __builtin_amdgcn_rcpf(den.y);
          if (k < 2) { r0[2 * k] = q0; r0[2 * k + 1] = q1; }
          else       { r1[2 * (k - 2)] = q0; r1[2 * (k - 2) + 1] = q1; }
        }
        *(v4f*)(Rs + u * 512 + lane * 4)       = r0;
        *(v4f*)(Rs + u * 512 + 256 + lane * 4) = r1;
      }
    };
    auto vload = [&](v4f (&V)[4], int blk) {
#pragma unroll
      for (int k = 0; k < 4; ++k) V[k] = *(const v4f*)(vg + blk * BLK + k * 4);
    };

    v4f V0[4], V1[4];
    vload(V0, 0);
    vload(V1, 1);
    rg_blk(V0, R0);                              // block 0
    __syncthreads();  // B0
#pragma unroll 1
    for (int i2 = 0; i2 < NBLK; i2 += 2) {
      if (i2 + 2 < NBLK) vload(V0, i2 + 2);      // prefetch vol for block i2+2
      rg_blk(V1, R1);                            // block i2+1
      __syncthreads();
      if (i2 + 3 < NBLK) vload(V1, i2 + 3);      // prefetch vol for block i2+3
      if (i2 + 2 < NBLK) rg_blk(V0, R0);         // block i2+2
      __syncthreads();
    }
  } else {
    // ========================= consumer wave =========================
    v2f a[4], bd[4], w[4], bias[4], cc[4];
#pragma unroll
    for (int j = 0; j < JPL; ++j) {
      int n = lane * JPL + j;
      float lam = -expf(llr[n]);
      float st  = expf(lstp[n]);
      float z   = st * lam;
      float ad  = (2.0f + z) / (2.0f - z);
      a[j >> 1][j & 1]    = ad;
      bd[j >> 1][j & 1]   = st * (1.0f + ad) * expf(logb[n]) * 0.5f;
      w[j >> 1][j & 1]    = lnw[n];
      bias[j >> 1][j & 1] = lnb[n];
      cc[j >> 1][j & 1]   = cvec[n];
    }
    v2f h[4];
#pragma unroll
    for (int k = 0; k < 4; ++k) h[k] = (v2f){0.0f, 0.0f};

    auto proc_blk = [&](const float* Xs, const float* Rs, float* SCs) {
      const float* xq = Xs + lane * 4;
      const float* rq = Rs + lane * 4;
      // step-0 preload; thereafter prefetch u+1 before computing u
      v4f xx0 = *(const v4f*)(xq);
      v4f xx1 = *(const v4f*)(xq + 256);
      v4f rr0 = *(const v4f*)(rq);
      v4f rr1 = *(const v4f*)(rq + 256);
#pragma unroll
      for (int u = 0; u < BLK; ++u) {
        v2f xs[4] = {lo2(xx0), hi2(xx0), lo2(xx1), hi2(xx1)};
        v2f rs[4] = {lo2(rr0), hi2(rr0), lo2(rr1), hi2(rr1)};
        if (u + 1 < BLK) {
          xx0 = *(const v4f*)(xq + (u + 1) * 512);
          xx1 = *(const v4f*)(xq + (u + 1) * 512 + 256);
          rr0 = *(const v4f*)(rq + (u + 1) * 512);
          rr1 = *(const v4f*)(rq + (u + 1) * 512 + 256);
        }

        v2f hr[4];
#pragma unroll
        for (int k = 0; k < 4; ++k)
          hr[k] = __builtin_elementwise_fma(a[k], h[k], bd[k] * xs[k]);

        v2f ts = (hr[0] + hr[1]) + (hr[2] + hr[3]);
        float s1 = ts.x + ts.y;
        v2f qs = (hr[0] * hr[0] + hr[1] * hr[1]) + (hr[2] * hr[2] + hr[3] * hr[3]);
        float s2 = qs.x + qs.y;

        wave_sum64x2(s1, s2);
        s1 = bcast63(s1);
        s2 = bcast63(s2);
        float mu  = s1 * (1.0f / DS);
        float m2  = s2 * (1.0f / DS);
        float var = __builtin_fmaf(-mu, mu, m2);
        float inv = __builtin_amdgcn_rsqf(var + 1e-5f);

#pragma unroll
        for (int k = 0; k < 4; ++k) {
          v2f niw = w[k] * inv;
          v2f hb  = bias[k] - niw * mu;
          v2f hln = __builtin_elementwise_fma(hr[k], niw, hb);
          h[k] = hln * rs[k];
        }

        v2f d = h[0] * cc[0];
        d = __builtin_elementwise_fma(h[1], cc[1], d);
        d = __builtin_elementwise_fma(h[2], cc[2], d);
        d = __builtin_elementwise_fma(h[3], cc[3], d);
        SCs[u * 64 + lane] = d.x + d.y;   // per-lane readout partial
      }
    };

    __syncthreads();  // B0
#pragma unroll 1
    for (int i2 = 0; i2 < NBLK; i2 += 2) {
      proc_blk(X0, R0, SC0);
      __syncthreads();
      proc_blk(X1, R1, SC1);
      __syncthreads();
    }
  }
}

// ------- epilogue: out = coef*x + c1*s[b,t] (s already reduced) -------
__global__ __launch_bounds__(256) void out_scalar(
    const float* __restrict__ x, const float* __restrict__ sp,
    const float* __restrict__ alpha_p, const float* __restrict__ logd_p,
    float* __restrict__ out)
{
  const int lane = threadIdx.x & 63;
  const size_t bt = (size_t)blockIdx.x * 4 + (threadIdx.x >> 6);

  float al   = 1.0f / (1.0f + expf(-alpha_p[0]));
  float dd   = expf(logd_p[0]);
  float coef = __builtin_fmaf(1.0f - al, dd, al);
  float c1   = 1.0f - al;

  float s = sp[bt] * c1;
  const v4f* x4 = (const v4f*)x;
  v4f* o4 = (v4f*)out;
  size_t base = bt * 128;
#pragma unroll
  for (int j = 0; j < 2; ++j) {
    size_t i = base + lane + (size_t)j * 64;
    v4f xv = x4[i];
    o4[i] = xv * coef + s;
  }
}

extern "C" void kernel_launch(void* const* d_in, const int* in_sizes, int n_in,
                              void* d_out, int out_size, void* d_ws, size_t ws_size,
                              hipStream_t stream) {
  const float* x    = (const float*)d_in[0];   // [8,4096,512]
  const float* vol  = (const float*)d_in[1];   // [8,4096,1]
  const float* llr  = (const float*)d_in[2];   // [512]
  const float* logb = (const float*)d_in[3];   // [512,1]
  const float* cvec = (const float*)d_in[4];   // [1,512]
  const float* logd = (const float*)d_in[5];   // [1]
  const float* lstp = (const float*)d_in[6];   // [512]
  const float* vgat = (const float*)d_in[7];   // [512]
  const float* alph = (const float*)d_in[8];   // [1]
  const float* lnw  = (const float*)d_in[9];   // [512]
  const float* lnb  = (const float*)d_in[10];  // [512]
  float* sp   = (float*)d_ws;                  // BATCH*SEQ floats = 128 KB
  float* outf = (float*)d_out;

  ssm_scan<<<BATCH, 192, 0, stream>>>(x, vol, llr, logb, cvec, lstp,
                                      vgat, lnw, lnb, sp);
  out_scalar<<<BATCH * SEQ / 4, 256, 0, stream>>>(x, sp, alph, logd, outf);
}